// Round 7
// baseline (217.325 us; speedup 1.0000x reference)
//
#include <hip/hip_runtime.h>

#define LOG2E 1.44269504088896340736f
#define SCL 0.18033688011111772f   // 0.125 * LOG2E

typedef __bf16 bf16x8 __attribute__((ext_vector_type(8)));
typedef float f32x16 __attribute__((ext_vector_type(16)));

union U4B { uint4 u; bf16x8 v; };

static __device__ __forceinline__ unsigned short f2bf(float f) {
  unsigned u = __builtin_bit_cast(unsigned, f);
  u += 0x7FFFu + ((u >> 16) & 1u);
  return (unsigned short)(u >> 16);
}
static __device__ __forceinline__ float bf2f(unsigned short s) {
  unsigned u = ((unsigned)s) << 16;
  return __builtin_bit_cast(float, u);
}
static __device__ __forceinline__ f32x16 zero16() {
  f32x16 z;
#pragma unroll
  for (int i = 0; i < 16; ++i) z[i] = 0.f;
  return z;
}
static __device__ __forceinline__ f32x16 MFMA(bf16x8 a, bf16x8 b, f32x16 c) {
  return __builtin_amdgcn_mfma_f32_32x32x16_bf16(a, b, c, 0, 0, 0);
}

// Transform a 32x32 C/D-layout f32x16 tile (lane: col=l&31, row=(r&3)+8*(r>>2)+4*hi)
// into two bf16x8 frags: frag[ch] elem e = T[16*ch + 8*hi + e][col].
static __device__ __forceinline__ void xform(f32x16 t, int hi, uint4& f0, uint4& f1) {
  unsigned pk[8], sw[8];
#pragma unroll
  for (int s = 0; s < 8; ++s) {
    unsigned d;
    asm("v_cvt_pk_bf16_f32 %0, %1, %2" : "=v"(d) : "v"(t[2*s]), "v"(t[2*s+1]));
    pk[s] = d;
  }
#pragma unroll
  for (int s = 0; s < 8; ++s) sw[s] = (unsigned)__shfl_xor((int)pk[s], 32);
  if (hi) {
    f0 = make_uint4(sw[2], sw[3], pk[2], pk[3]);
    f1 = make_uint4(sw[6], sw[7], pk[6], pk[7]);
  } else {
    f0 = make_uint4(pk[0], pk[1], sw[0], sw[1]);
    f1 = make_uint4(pk[4], pk[5], sw[4], sw[5]);
  }
}

__global__ void zero_out_k(float* __restrict__ out, int n) {
  int i = blockIdx.x * 256 + threadIdx.x;
  if (i < n) out[i] = 0.f;
}

__global__ void setup_k(
    const float* __restrict__ wq_w, const float* __restrict__ wq_b,
    const float* __restrict__ wk_w, const float* __restrict__ wk_b,
    const float* __restrict__ wv_w, const float* __restrict__ wv_b,
    const float* __restrict__ dense_w, float* __restrict__ ws)
{
  int gid = blockIdx.x*256 + threadIdx.x;
  float* pe = ws;                                        // 2560 f32
  unsigned short* wqT = (unsigned short*)(ws + 2560);    // [512][32] bf16 (t<20 w, t==20 bias, else 0)
  unsigned short* wkT = (unsigned short*)(ws + 10752);
  float* WVD = ws + 18944;                               // [8][10][10]
  float* bvd = ws + 19744;                               // [8][10]
  if (gid < 2560) {
    int i = gid/10, t = gid%10;
    double ex = (double)(2*(t/2)) / 10.0;
    double ang = (double)i * pow(10000.0, -ex);
    pe[gid] = (float)((t & 1) ? cos(ang) : sin(ang));
  } else if (gid < 2560 + 16384) {
    int idx = gid - 2560;
    int hd = idx >> 5, t = idx & 31;
    float v = (t < 20) ? wq_w[t*512 + hd] : ((t == 20) ? wq_b[hd] : 0.f);
    wqT[idx] = f2bf(v);
  } else if (gid < 2560 + 32768) {
    int idx = gid - (2560 + 16384);
    int hd = idx >> 5, t = idx & 31;
    float v = (t < 20) ? wk_w[t*512 + hd] : ((t == 20) ? wk_b[hd] : 0.f);
    wkT[idx] = f2bf(v);
  } else if (gid < 2560 + 32768 + 800) {
    int idx = gid - (2560 + 32768);
    int h = idx/100, rem = idx%100, t = rem/10, w = rem%10;
    float s = 0.f;
    for (int d = 0; d < 64; ++d) s += wv_w[t*512 + h*64 + d] * dense_w[(h*64 + d)*10 + w];
    WVD[idx] = s;
  } else if (gid < 2560 + 32768 + 880) {
    int idx = gid - (2560 + 32768 + 800);
    int h = idx/10, w = idx%10;
    float s = 0.f;
    for (int d = 0; d < 64; ++d) s += wv_b[h*64 + d] * dense_w[(h*64 + d)*10 + w];
    bvd[idx] = s;
  }
}

// Grid 768: block = (bc, p3). p3 handles heads {0-2},{3-5},{6-7}; atomicAdd to out.
// NOTE 1: __launch_bounds__ second arg MUST stay 1 — every build with >=2 NaN'd
// (5-round empirical pattern), every build with 1 passed.
// NOTE 2 (this round's experiment): k_lds deleted; K-tile A-frags recomputed
// per-wave in registers (identical arithmetic). LDS 54.3KB -> 20.6KB to test
// the "LDS caps us at 1 block/CU" hypothesis (per-unit throughput flat across
// R1/R3/R6 despite grid scaling => no co-residency ever happened).
__global__ __launch_bounds__(256, 1) void mha_fused(
    const float* __restrict__ x,
    const float* __restrict__ dense_w, const float* __restrict__ dense_b,
    const unsigned short* __restrict__ wqT, const unsigned short* __restrict__ wkT,
    const float* __restrict__ WVD, const float* __restrict__ bvd,
    const float* __restrict__ pe,
    float* __restrict__ out)
{
  __shared__ __align__(16) unsigned short qk_in[256*24];  // [win][24] bf16: dd[i+2](10), dd[i](10), 1.0, 0,0,0
  __shared__ __align__(16) unsigned short vdT[16*256];    // [w][key] bf16, granule XOR (w&15); rows 0..9 valid
  __shared__ unsigned short mean_b[256];                  // mean*0.1 as bf16
  __shared__ unsigned long long padb[4];
  __shared__ float ddmean_s[10];

  const int tid = threadIdx.x;
  const int lane = tid & 63;
  const int wv = tid >> 6;
  const int hi = lane >> 5;
  const int cc = lane & 31;
  const int bc = blockIdx.x / 3;
  const int p3 = blockIdx.x - bc*3;
  const int hbase = p3*3;
  const int nh = (p3 == 2) ? 2 : 3;

  // ---- A1: load x[win=tid], mean/minmask, ddr = data+pe; mmv into vdT rows 2-3 ----
  float ddr[10];
  {
    const float* xb = x + ((size_t)bc*2560 + tid*10)*3;
    float dat[10], msk[10];
#pragma unroll
    for (int t = 0; t < 10; ++t) { dat[t] = xb[3*t]; msk[t] = xb[3*t+2]; }
    float mean = 0.f, mm = msk[0];
#pragma unroll
    for (int t = 0; t < 10; ++t) { mean += dat[t]*msk[t]; mm = fminf(mm, msk[t]); }
    mean_b[tid] = f2bf(mean * 0.1f);
    const float* per = pe + tid*10;
#pragma unroll
    for (int t = 0; t < 10; ++t) ddr[t] = dat[t] + per[t];
    float* mmv = (float*)&vdT[512];      // vdT rows 2-3 as f32[256] (bytes 1024..2048)
    mmv[tid] = mm;
  }
  __syncthreads();
  // ---- A2: qk_in (re-load x for win tid+2), padbits, zero vdT rows 10-15 ----
  {
    const float* mmv = (const float*)&vdT[512];
    if (tid < 254) {
      const float* xb2 = x + ((size_t)bc*2560 + (tid+2)*10)*3;
      const float* per2 = pe + (tid+2)*10;
#pragma unroll
      for (int t = 0; t < 10; ++t) qk_in[tid*24 + t] = f2bf(xb2[3*t] + per2[t]);
#pragma unroll
      for (int t = 0; t < 10; ++t) qk_in[tid*24 + 10 + t] = f2bf(ddr[t]);
      qk_in[tid*24 + 20] = 0x3F80;   // bias 1.0
      qk_in[tid*24 + 21] = 0; qk_in[tid*24 + 22] = 0; qk_in[tid*24 + 23] = 0;
    } else {
#pragma unroll
      for (int t = 0; t < 24; ++t) qk_in[tid*24 + t] = 0;
    }
#pragma unroll
    for (int i = 0; i < 6; ++i) vdT[(10 + i)*256 + tid] = 0;
    // padding[key=tid] from window tid+1; keys 254/255 always masked (pad keys)
    bool cond = (tid >= 254) || (mmv[tid+1] == 0.0f);
    unsigned long long bl = __ballot(cond);
    if (lane == 0) padb[wv] = bl;
  }
  __syncthreads();
  // ---- A3: ddmean partial sums from qk_in bf16 (part aliases vdT rows 0-1, 640B) ----
  {
    float* part = (float*)vdT;
    if (tid < 160) {
      int t = tid >> 4, j = tid & 15;
      int w0 = 1 + j*16, w1 = (w0 + 16 < 255) ? (w0 + 16) : 255;
      float s = 0.f;
      for (int w = w0; w < w1; ++w)
        s += (w < 254) ? bf2f(qk_in[w*24 + 10 + t]) : bf2f(qk_in[252*24 + t]);
      part[tid] = s;
    }
  }
  __syncthreads();
  if (tid < 10) {
    const float* part = (const float*)vdT;
    float s = 0.f;
#pragma unroll
    for (int j = 0; j < 16; ++j) s += part[tid*16 + j];
    ddmean_s[tid] = s * (1.0f/254.0f);
  }
  float dwcol = 0.f, dbias = 0.f;
  if (cc < 10) { dwcol = dense_w[5120 + cc]; dbias = dense_b[cc]; }
  const unsigned* pw = (const unsigned*)padb;

  f32x16 outacc0 = zero16(), outacc1 = zero16();

#pragma unroll 1
  for (int hh = 0; hh < nh; ++hh) {
    const int h = hbase + hh;
    __syncthreads();   // prior head's vdT reads + phase-A part/ddmean done
    // ---- stage VD^T = (dd[1..254] @ WVD_h + bvd_h)^T, bf16, swizzled ----
    if (tid < 254) {
      float df[10];
      int src = tid + 1;
      if (src <= 253) {
#pragma unroll
        for (int t = 0; t < 10; ++t) df[t] = bf2f(qk_in[src*24 + 10 + t]);   // dd[src]
      } else {
#pragma unroll
        for (int t = 0; t < 10; ++t) df[t] = bf2f(qk_in[252*24 + t]);        // dd[254]
      }
      const float* wvd = WVD + h*100;
      const float* bv = bvd + h*10;
#pragma unroll
      for (int w = 0; w < 10; ++w) {
        float s = bv[w];
#pragma unroll
        for (int t = 0; t < 10; ++t) s += df[t]*wvd[t*10 + w];
        vdT[w*256 + (tid ^ ((w & 15)*8))] = f2bf(s);
      }
    }
    if (tid < 20) {   // zero pad-keys 254/255 in rows 0..9 (avoid NaN*0 in mfma)
      int w = tid >> 1, j = 254 + (tid & 1);
      vdT[w*256 + (j ^ ((w & 15)*8))] = 0;
    }
    // meanVD for degenerate (fully-padded) query rows: colmean of VD_h
    float mvd = 0.f;
    if (cc < 10) {
      mvd = bvd[h*10 + cc];
#pragma unroll
      for (int t = 0; t < 10; ++t) mvd = fmaf(ddmean_s[t], WVD[h*100 + t*10 + cc], mvd);
    }
    __syncthreads();

    // ---- hoist Wk A-frags for this head (key-independent) ----
    U4B wk00, wk01, wk10, wk11;
    wk00.u = *(const uint4*)&wkT[(h*64 + cc)*32 + 8*hi];
    wk01.u = *(const uint4*)&wkT[(h*64 + cc)*32 + 16 + 8*hi];
    wk10.u = *(const uint4*)&wkT[(h*64 + 32 + cc)*32 + 8*hi];
    wk11.u = *(const uint4*)&wkT[(h*64 + 32 + cc)*32 + 16 + 8*hi];

    // ---- attention: wave wv owns query tiles {wv, 7-wv} (causal work = 9 tiles) ----
#pragma unroll
    for (int qti = 0; qti < 2; ++qti) {
      const int qt = qti ? (7 - wv) : wv;
      const int qrow = 32*qt + cc;
      // Q projection (swapped) -> B-frags in regs
      uint4 qf0, qf1, qf2, qf3;
      {
        U4B b0, b1;
        b0.u = *(const uint4*)&qk_in[qrow*24 + 8*hi];
        b1.u = make_uint4(0,0,0,0);
        if (!hi) b1.u = *(const uint4*)&qk_in[qrow*24 + 16];
        {
          const unsigned short* wrow = wqT + (h*64 + cc)*32;
          U4B a0, a1;
          a0.u = *(const uint4*)&wrow[8*hi];
          a1.u = *(const uint4*)&wrow[16 + 8*hi];
          f32x16 acc = zero16();
          acc = MFMA(a0.v, b0.v, acc);
          acc = MFMA(a1.v, b1.v, acc);
          xform(acc, hi, qf0, qf1);
        }
        {
          const unsigned short* wrow = wqT + (h*64 + 32 + cc)*32;
          U4B a0, a1;
          a0.u = *(const uint4*)&wrow[8*hi];
          a1.u = *(const uint4*)&wrow[16 + 8*hi];
          f32x16 acc = zero16();
          acc = MFMA(a0.v, b0.v, acc);
          acc = MFMA(a1.v, b1.v, acc);
          xform(acc, hi, qf2, qf3);
        }
      }
      // ---- single-pass masked-exp softmax (m = 0; logits tiny) + PV ----
      float sum = 0.f;
      f32x16 pv = zero16();
      const int vrow = cc & 15;
      const int vsw = 8*vrow;
#pragma unroll
      for (int kt = 0; kt < 8; ++kt) {
        if (kt <= qt) {
          // K-tile A-frags recomputed in regs (replaces k_lds staging)
          const int kr = 32*kt + cc;
          U4B kb0, kb1;
          kb0.u = *(const uint4*)&qk_in[kr*24 + 8*hi];
          kb1.u = make_uint4(0,0,0,0);
          if (!hi) kb1.u = *(const uint4*)&qk_in[kr*24 + 16];
          uint4 kf0, kf1, kf2, kf3;
          {
            f32x16 acc = zero16();
            acc = MFMA(wk00.v, kb0.v, acc);
            acc = MFMA(wk01.v, kb1.v, acc);
            xform(acc, hi, kf0, kf1);
          }
          {
            f32x16 acc = zero16();
            acc = MFMA(wk10.v, kb0.v, acc);
            acc = MFMA(wk11.v, kb1.v, acc);
            xform(acc, hi, kf2, kf3);
          }
          f32x16 a = zero16();
          U4B ka, qa;
          ka.u = kf0; qa.u = qf0; a = MFMA(ka.v, qa.v, a);
          ka.u = kf1; qa.u = qf1; a = MFMA(ka.v, qa.v, a);
          ka.u = kf2; qa.u = qf2; a = MFMA(ka.v, qa.v, a);
          ka.u = kf3; qa.u = qf3; a = MFMA(ka.v, qa.v, a);
          const unsigned pbk = pw[kt];
          if (kt < qt) {        // non-diagonal: padding mask only
#pragma unroll
            for (int r = 0; r < 16; ++r) {
              const int base = (r & 3) + 8*(r >> 2);
              const int pos = base + 4*hi;
              float add = ((pbk >> pos) & 1u) ? -2.0e9f : 0.0f;
              float p = exp2f(fmaf(a[r], SCL, add));
              a[r] = p;
              sum += p;
            }
          } else {              // diagonal: padding + causal
#pragma unroll
            for (int r = 0; r < 16; ++r) {
              const int base = (r & 3) + 8*(r >> 2);
              const int pos = base + 4*hi;
              bool mk = (((pbk >> pos) & 1u) != 0u) || (pos > cc);
              float add = mk ? -2.0e9f : 0.0f;
              float p = exp2f(fmaf(a[r], SCL, add));
              a[r] = p;
              sum += p;
            }
          }
          // P -> A-frags, PV MFMA
          uint4 pa0, pa1;
          xform(a, hi, pa0, pa1);
          U4B pA, vB;
          pA.u = pa0;
          vB.u = *(const uint4*)&vdT[vrow*256 + ((32*kt + 8*hi) ^ vsw)];
          pv = MFMA(pA.v, vB.v, pv);
          pA.u = pa1;
          vB.u = *(const uint4*)&vdT[vrow*256 + ((32*kt + 16 + 8*hi) ^ vsw)];
          pv = MFMA(pA.v, vB.v, pv);
        }
      }
      float stot = sum + __shfl_xor(sum, 32);
      // clamp: degenerate rows give stot==0; keep rs finite, degq select substitutes mvd
      const float rs = 1.0f / fmaxf(stot, 1e-30f);
      // ---- degenerate (all keys <= q padded) -> substitute column-mean of VD ----
      bool pre = true;
#pragma unroll
      for (int j = 0; j < 8; ++j) { if (j < qt) pre = pre && (pw[j] == 0xFFFFFFFFu); }
      const unsigned pbq = pw[qt];
#pragma unroll
      for (int r = 0; r < 16; ++r) {
        const int base = (r & 3) + 8*(r >> 2);
        const int qr = base + 4*hi;
        unsigned lm = (qr == 31) ? 0xFFFFFFFFu : ((2u << qr) - 1u);
        bool degq = pre && ((pbq & lm) == lm);
        float rr = __shfl(rs, qr, 32);
        float contrib = degq ? mvd : pv[r]*rr;
        if (qti == 0) outacc0[r] += contrib; else outacc1[r] += contrib;
      }
    }
  }

  // ---- epilogue: atomicAdd partial sums; p3 0 adds mean term + bias ----
#pragma unroll
  for (int qti = 0; qti < 2; ++qti) {
    const int qt = qti ? (7 - wv) : wv;
#pragma unroll
    for (int r = 0; r < 16; ++r) {
      const int base = (r & 3) + 8*(r >> 2);
      int q = 32*qt + base + 4*hi;
      if (q < 254 && cc < 10) {
        float v = (qti == 0 ? outacc0[r] : outacc1[r]);
        if (p3 == 0) v += bf2f(mean_b[q + 1])*dwcol + dbias;
        atomicAdd(&out[((size_t)bc*254 + q)*10 + cc], v);
      }
    }
  }
}

extern "C" void kernel_launch(void* const* d_in, const int* in_sizes, int n_in,
                              void* d_out, int out_size, void* d_ws, size_t ws_size,
                              hipStream_t stream) {
  const float* x       = (const float*)d_in[0];
  const float* wq_w    = (const float*)d_in[1];
  const float* wq_b    = (const float*)d_in[2];
  const float* wk_w    = (const float*)d_in[3];
  const float* wk_b    = (const float*)d_in[4];
  const float* wv_w    = (const float*)d_in[5];
  const float* wv_b    = (const float*)d_in[6];
  const float* dense_w = (const float*)d_in[7];
  const float* dense_b = (const float*)d_in[8];
  float* ws = (float*)d_ws;

  zero_out_k<<<(out_size + 255)/256, 256, 0, stream>>>((float*)d_out, out_size);
  setup_k<<<142, 256, 0, stream>>>(wq_w, wq_b, wk_w, wk_b, wv_w, wv_b, dense_w, ws);
  mha_fused<<<768, 256, 0, stream>>>(
      x, dense_w, dense_b,
      (const unsigned short*)(ws + 2560),   // wqT
      (const unsigned short*)(ws + 10752),  // wkT
      ws + 18944,                           // WVD
      ws + 19744,                           // bvd
      ws,                                   // pe
      (float*)d_out);
}

// Round 8
// 198.349 us; speedup vs baseline: 1.0957x; 1.0957x over previous
//
#include <hip/hip_runtime.h>

#define LOG2E 1.44269504088896340736f
#define SCL 0.18033688011111772f   // 0.125 * LOG2E

typedef __bf16 bf16x8 __attribute__((ext_vector_type(8)));
typedef float f32x16 __attribute__((ext_vector_type(16)));

union U4B { uint4 u; bf16x8 v; };

static __device__ __forceinline__ unsigned short f2bf(float f) {
  unsigned u = __builtin_bit_cast(unsigned, f);
  u += 0x7FFFu + ((u >> 16) & 1u);
  return (unsigned short)(u >> 16);
}
static __device__ __forceinline__ float bf2f(unsigned short s) {
  unsigned u = ((unsigned)s) << 16;
  return __builtin_bit_cast(float, u);
}
static __device__ __forceinline__ f32x16 zero16() {
  f32x16 z;
#pragma unroll
  for (int i = 0; i < 16; ++i) z[i] = 0.f;
  return z;
}
static __device__ __forceinline__ f32x16 MFMA(bf16x8 a, bf16x8 b, f32x16 c) {
  return __builtin_amdgcn_mfma_f32_32x32x16_bf16(a, b, c, 0, 0, 0);
}

// Transform a 32x32 C/D-layout f32x16 tile (lane: col=l&31, row=(r&3)+8*(r>>2)+4*hi)
// into two bf16x8 frags: frag[ch] elem e = T[16*ch + 8*hi + e][col].
static __device__ __forceinline__ void xform(f32x16 t, int hi, uint4& f0, uint4& f1) {
  unsigned pk[8], sw[8];
#pragma unroll
  for (int s = 0; s < 8; ++s) {
    unsigned d;
    asm("v_cvt_pk_bf16_f32 %0, %1, %2" : "=v"(d) : "v"(t[2*s]), "v"(t[2*s+1]));
    pk[s] = d;
  }
#pragma unroll
  for (int s = 0; s < 8; ++s) sw[s] = (unsigned)__shfl_xor((int)pk[s], 32);
  if (hi) {
    f0 = make_uint4(sw[2], sw[3], pk[2], pk[3]);
    f1 = make_uint4(sw[6], sw[7], pk[6], pk[7]);
  } else {
    f0 = make_uint4(pk[0], pk[1], sw[0], sw[1]);
    f1 = make_uint4(pk[4], pk[5], sw[4], sw[5]);
  }
}

// Merged prep: zero d_out (all 2540 blocks) + setup tables (blocks with gid<36208).
// Disjoint output buffers -> no race.
__global__ void prep_k(
    const float* __restrict__ wq_w, const float* __restrict__ wq_b,
    const float* __restrict__ wk_w, const float* __restrict__ wk_b,
    const float* __restrict__ wv_w, const float* __restrict__ wv_b,
    const float* __restrict__ dense_w, float* __restrict__ ws,
    float* __restrict__ out, int out_size)
{
  int gid = blockIdx.x*256 + threadIdx.x;
  if (gid < out_size) out[gid] = 0.f;
  float* pe = ws;                                        // 2560 f32
  unsigned short* wqT = (unsigned short*)(ws + 2560);    // [512][32] bf16 (t<20 w, t==20 bias, else 0)
  unsigned short* wkT = (unsigned short*)(ws + 10752);
  float* WVD = ws + 18944;                               // [8][10][10]
  float* bvd = ws + 19744;                               // [8][10]
  if (gid < 2560) {
    int i = gid/10, t = gid%10;
    double ex = (double)(2*(t/2)) / 10.0;
    double ang = (double)i * pow(10000.0, -ex);
    pe[gid] = (float)((t & 1) ? cos(ang) : sin(ang));
  } else if (gid < 2560 + 16384) {
    int idx = gid - 2560;
    int hd = idx >> 5, t = idx & 31;
    float v = (t < 20) ? wq_w[t*512 + hd] : ((t == 20) ? wq_b[hd] : 0.f);
    wqT[idx] = f2bf(v);
  } else if (gid < 2560 + 32768) {
    int idx = gid - (2560 + 16384);
    int hd = idx >> 5, t = idx & 31;
    float v = (t < 20) ? wk_w[t*512 + hd] : ((t == 20) ? wk_b[hd] : 0.f);
    wkT[idx] = f2bf(v);
  } else if (gid < 2560 + 32768 + 800) {
    int idx = gid - (2560 + 32768);
    int h = idx/100, rem = idx%100, t = rem/10, w = rem%10;
    float s = 0.f;
    for (int d = 0; d < 64; ++d) s += wv_w[t*512 + h*64 + d] * dense_w[(h*64 + d)*10 + w];
    WVD[idx] = s;
  } else if (gid < 2560 + 32768 + 880) {
    int idx = gid - (2560 + 32768 + 800);
    int h = idx/10, w = idx%10;
    float s = 0.f;
    for (int d = 0; d < 64; ++d) s += wv_b[h*64 + d] * dense_w[(h*64 + d)*10 + w];
    bvd[idx] = s;
  }
}

// Grid 768: block = (bc, p3). p3 handles heads {0-2},{3-5},{6-7}; atomicAdd to out.
// NOTE 1: launch_bounds min-waves arg MUST NOT be >=2 — every such build NaN'd
// (5-round empirical pattern). This round: SINGLE-ARG launch_bounds (no
// waves-per-eu metadata at all) to test whether the (256,1) attribute was
// capping residency at 1 block/CU (occupancy pinned at ~10.4% across 7 rounds
// despite LDS 63->21KB, VGPR 256->152, grid 256->768; per-kt throughput flat).
__global__ __launch_bounds__(256) void mha_fused(
    const float* __restrict__ x,
    const float* __restrict__ dense_w, const float* __restrict__ dense_b,
    const unsigned short* __restrict__ wqT, const unsigned short* __restrict__ wkT,
    const float* __restrict__ WVD, const float* __restrict__ bvd,
    const float* __restrict__ pe,
    float* __restrict__ out)
{
  __shared__ __align__(16) unsigned short qk_in[256*24];  // [win][24] bf16: dd[i+2](10), dd[i](10), 1.0, 0,0,0
  __shared__ __align__(16) unsigned short k_lds[256*64];  // [key][64] bf16 A-frags, 16B-granule XOR (key&7)
  __shared__ __align__(16) unsigned short vdT[16*256];    // [w][key] bf16, granule XOR (w&15); rows 0..9 valid
  __shared__ unsigned short mean_b[256];                  // mean*0.1 as bf16
  __shared__ unsigned long long padb[4];
  __shared__ float ddmean_s[10];

  const int tid = threadIdx.x;
  const int lane = tid & 63;
  const int wv = tid >> 6;
  const int hi = lane >> 5;
  const int cc = lane & 31;
  const int bc = blockIdx.x / 3;
  const int p3 = blockIdx.x - bc*3;
  const int hbase = p3*3;
  const int nh = (p3 == 2) ? 2 : 3;

  // ---- Phase A: load x, mean/minmask, dd = data+pe, build qk_in + padbits + ddmean ----
  float ddr[10];
  {
    const float* xb = x + ((size_t)bc*2560 + tid*10)*3;
    float dat[10], msk[10];
#pragma unroll
    for (int t = 0; t < 10; ++t) { dat[t] = xb[3*t]; msk[t] = xb[3*t+2]; }
    float mean = 0.f, mm = msk[0];
#pragma unroll
    for (int t = 0; t < 10; ++t) { mean += dat[t]*msk[t]; mm = fminf(mm, msk[t]); }
    mean_b[tid] = f2bf(mean * 0.1f);
    const float* per = pe + tid*10;
#pragma unroll
    for (int t = 0; t < 10; ++t) ddr[t] = dat[t] + per[t];
    float* ddtmp = (float*)k_lds;        // alias k_lds during phase A
    float* mmv = ddtmp + 2560;
#pragma unroll
    for (int t = 0; t < 10; ++t) ddtmp[tid*10 + t] = ddr[t];
    mmv[tid] = mm;
  }
  __syncthreads();
  {
    const float* ddtmp = (const float*)k_lds;
    const float* mmv = ddtmp + 2560;
    float* part = (float*)vdT;           // alias vdT rows 0-1 during phase A2
    if (tid < 254) {
#pragma unroll
      for (int t = 0; t < 10; ++t) qk_in[tid*24 + t] = f2bf(ddtmp[(tid+2)*10 + t]);
#pragma unroll
      for (int t = 0; t < 10; ++t) qk_in[tid*24 + 10 + t] = f2bf(ddr[t]);
      qk_in[tid*24 + 20] = 0x3F80;   // bias 1.0
      qk_in[tid*24 + 21] = 0; qk_in[tid*24 + 22] = 0; qk_in[tid*24 + 23] = 0;
    } else {
#pragma unroll
      for (int t = 0; t < 24; ++t) qk_in[tid*24 + t] = 0;
    }
    // partial sums for ddmean (mean over dd[1..254])
    if (tid < 160) {
      int t = tid >> 4, j = tid & 15;
      int w0 = 1 + j*16, w1 = (w0 + 16 < 255) ? (w0 + 16) : 255;
      float s = 0.f;
      for (int w = w0; w < w1; ++w) s += ddtmp[w*10 + t];
      part[tid] = s;
    }
    // zero vdT rows 10..15 once (never written by staging; read by PV's discarded
    // B-columns -> must not be uninitialized LDS). Disjoint from part (rows 0-1).
#pragma unroll
    for (int i = 0; i < 6; ++i) vdT[(10 + i)*256 + tid] = 0;
    // padding[key=tid] from window tid+1; keys 254/255 always masked (pad keys)
    bool cond = (tid >= 254) || (mmv[tid+1] == 0.0f);
    unsigned long long bl = __ballot(cond);
    if (lane == 0) padb[wv] = bl;
  }
  __syncthreads();
  if (tid < 10) {
    const float* part = (const float*)vdT;
    float s = 0.f;
#pragma unroll
    for (int j = 0; j < 16; ++j) s += part[tid*16 + j];
    ddmean_s[tid] = s * (1.0f/254.0f);
  }
  float dwcol = 0.f, dbias = 0.f;
  if (cc < 10) { dwcol = dense_w[5120 + cc]; dbias = dense_b[cc]; }
  const unsigned* pw = (const unsigned*)padb;

  f32x16 outacc0 = zero16(), outacc1 = zero16();

#pragma unroll 1
  for (int hh = 0; hh < nh; ++hh) {
    const int h = hbase + hh;
    __syncthreads();   // prior head's attention reads done (and phase-A LDS ready)
    // ---- stage VD^T = (dd[1..254] @ WVD_h + bvd_h)^T, bf16, swizzled ----
    if (tid < 254) {
      float df[10];
      int src = tid + 1;
      if (src <= 253) {
#pragma unroll
        for (int t = 0; t < 10; ++t) df[t] = bf2f(qk_in[src*24 + 10 + t]);   // dd[src]
      } else {
#pragma unroll
        for (int t = 0; t < 10; ++t) df[t] = bf2f(qk_in[252*24 + t]);        // dd[254]
      }
      const float* wvd = WVD + h*100;
      const float* bv = bvd + h*10;
#pragma unroll
      for (int w = 0; w < 10; ++w) {
        float s = bv[w];
#pragma unroll
        for (int t = 0; t < 10; ++t) s += df[t]*wvd[t*10 + w];
        vdT[w*256 + (tid ^ ((w & 15)*8))] = f2bf(s);
      }
    }
    if (tid < 32) {   // zero pad-keys 254/255 in rows 0..15 (avoid NaN*0 in mfma)
      int w = tid >> 1, j = 254 + (tid & 1);
      vdT[w*256 + (j ^ ((w & 15)*8))] = 0;
    }
    // meanVD for degenerate (fully-padded) query rows: colmean of VD_h
    float mvd = 0.f;
    if (cc < 10) {
      mvd = bvd[h*10 + cc];
#pragma unroll
      for (int t = 0; t < 10; ++t) mvd = fmaf(ddmean_s[t], WVD[h*100 + t*10 + cc], mvd);
    }
    __syncthreads();

    // ---- K projection (swapped): KT = WK'_h x qk_in^T, write A-frags to k_lds ----
#pragma unroll
    for (int jti = 0; jti < 2; ++jti) {
      int jt = wv + 4*jti;
      int krow = 32*jt + cc;
      U4B b0, b1;
      b0.u = *(const uint4*)&qk_in[krow*24 + 8*hi];
      b1.u = make_uint4(0,0,0,0);
      if (!hi) b1.u = *(const uint4*)&qk_in[krow*24 + 16];
#pragma unroll
      for (int it = 0; it < 2; ++it) {
        const unsigned short* wrow = wkT + (h*64 + 32*it + cc)*32;
        U4B a0, a1;
        a0.u = *(const uint4*)&wrow[8*hi];
        a1.u = *(const uint4*)&wrow[16 + 8*hi];
        f32x16 acc = zero16();
        acc = MFMA(a0.v, b0.v, acc);
        acc = MFMA(a1.v, b1.v, acc);
        uint4 f0, f1;
        xform(acc, hi, f0, f1);
        int dc0 = 2*it, dc1 = 2*it + 1;
        *(uint4*)&k_lds[krow*64 + ((8*(2*dc0 + hi)) ^ (8*(krow & 7)))] = f0;
        *(uint4*)&k_lds[krow*64 + ((8*(2*dc1 + hi)) ^ (8*(krow & 7)))] = f1;
      }
    }
    __syncthreads();

    // ---- attention: wave wv owns query tiles {wv, 7-wv} (causal work = 9 tiles, balanced) ----
#pragma unroll
    for (int qti = 0; qti < 2; ++qti) {
      const int qt = qti ? (7 - wv) : wv;
      const int qrow = 32*qt + cc;
      // Q projection (swapped) -> B-frags in regs
      uint4 qf0, qf1, qf2, qf3;
      {
        U4B b0, b1;
        b0.u = *(const uint4*)&qk_in[qrow*24 + 8*hi];
        b1.u = make_uint4(0,0,0,0);
        if (!hi) b1.u = *(const uint4*)&qk_in[qrow*24 + 16];
        {
          const unsigned short* wrow = wqT + (h*64 + cc)*32;
          U4B a0, a1;
          a0.u = *(const uint4*)&wrow[8*hi];
          a1.u = *(const uint4*)&wrow[16 + 8*hi];
          f32x16 acc = zero16();
          acc = MFMA(a0.v, b0.v, acc);
          acc = MFMA(a1.v, b1.v, acc);
          xform(acc, hi, qf0, qf1);
        }
        {
          const unsigned short* wrow = wqT + (h*64 + 32 + cc)*32;
          U4B a0, a1;
          a0.u = *(const uint4*)&wrow[8*hi];
          a1.u = *(const uint4*)&wrow[16 + 8*hi];
          f32x16 acc = zero16();
          acc = MFMA(a0.v, b0.v, acc);
          acc = MFMA(a1.v, b1.v, acc);
          xform(acc, hi, qf2, qf3);
        }
      }
      // ---- single-pass masked-exp softmax (m = 0; logits are tiny) + PV ----
      float sum = 0.f;
      f32x16 pv = zero16();
      const int vrow = cc & 15;
      const int vsw = 8*vrow;
#pragma unroll
      for (int kt = 0; kt < 8; ++kt) {
        if (kt <= qt) {
          const int kr = 32*kt + cc;
          const int kbase = kr*64;
          const int ksw = 8*(kr & 7);
          f32x16 a = zero16();
          U4B ka, qa;
          ka.u = *(const uint4*)&k_lds[kbase + ((8*(0 + hi)) ^ ksw)];
          qa.u = qf0; a = MFMA(ka.v, qa.v, a);
          ka.u = *(const uint4*)&k_lds[kbase + ((8*(2 + hi)) ^ ksw)];
          qa.u = qf1; a = MFMA(ka.v, qa.v, a);
          ka.u = *(const uint4*)&k_lds[kbase + ((8*(4 + hi)) ^ ksw)];
          qa.u = qf2; a = MFMA(ka.v, qa.v, a);
          ka.u = *(const uint4*)&k_lds[kbase + ((8*(6 + hi)) ^ ksw)];
          qa.u = qf3; a = MFMA(ka.v, qa.v, a);
          const unsigned pbk = pw[kt];
          if (kt < qt) {        // non-diagonal: padding mask only
#pragma unroll
            for (int r = 0; r < 16; ++r) {
              const int base = (r & 3) + 8*(r >> 2);
              const int pos = base + 4*hi;
              float add = ((pbk >> pos) & 1u) ? -2.0e9f : 0.0f;
              float p = exp2f(fmaf(a[r], SCL, add));
              a[r] = p;
              sum += p;
            }
          } else {              // diagonal: padding + causal
#pragma unroll
            for (int r = 0; r < 16; ++r) {
              const int base = (r & 3) + 8*(r >> 2);
              const int pos = base + 4*hi;
              bool mk = (((pbk >> pos) & 1u) != 0u) || (pos > cc);
              float add = mk ? -2.0e9f : 0.0f;
              float p = exp2f(fmaf(a[r], SCL, add));
              a[r] = p;
              sum += p;
            }
          }
          // P -> A-frags, PV MFMA
          uint4 pa0, pa1;
          xform(a, hi, pa0, pa1);
          U4B pA, vB;
          pA.u = pa0;
          vB.u = *(const uint4*)&vdT[vrow*256 + ((32*kt + 8*hi) ^ vsw)];
          pv = MFMA(pA.v, vB.v, pv);
          pA.u = pa1;
          vB.u = *(const uint4*)&vdT[vrow*256 + ((32*kt + 16 + 8*hi) ^ vsw)];
          pv = MFMA(pA.v, vB.v, pv);
        }
      }
      float stot = sum + __shfl_xor(sum, 32);
      // clamp: degenerate rows give stot==0; keep rs finite (0*rs=0), degq select
      // below substitutes mvd. No inf/NaN on any path.
      const float rs = 1.0f / fmaxf(stot, 1e-30f);
      // ---- degenerate (all keys <= q padded) -> substitute column-mean of VD ----
      bool pre = true;
#pragma unroll
      for (int j = 0; j < 8; ++j) { if (j < qt) pre = pre && (pw[j] == 0xFFFFFFFFu); }
      const unsigned pbq = pw[qt];
#pragma unroll
      for (int r = 0; r < 16; ++r) {
        const int base = (r & 3) + 8*(r >> 2);
        const int qr = base + 4*hi;
        unsigned lm = (qr == 31) ? 0xFFFFFFFFu : ((2u << qr) - 1u);
        bool degq = pre && ((pbq & lm) == lm);
        float rr = __shfl(rs, qr, 32);
        float contrib = degq ? mvd : pv[r]*rr;
        if (qti == 0) outacc0[r] += contrib; else outacc1[r] += contrib;
      }
    }
  }

  // ---- epilogue: atomicAdd partial sums; p3 0 adds mean term + bias ----
#pragma unroll
  for (int qti = 0; qti < 2; ++qti) {
    const int qt = qti ? (7 - wv) : wv;
#pragma unroll
    for (int r = 0; r < 16; ++r) {
      const int base = (r & 3) + 8*(r >> 2);
      int q = 32*qt + base + 4*hi;
      if (q < 254 && cc < 10) {
        float v = (qti == 0 ? outacc0[r] : outacc1[r]);
        if (p3 == 0) v += bf2f(mean_b[q + 1])*dwcol + dbias;
        atomicAdd(&out[((size_t)bc*254 + q)*10 + cc], v);
      }
    }
  }
}

extern "C" void kernel_launch(void* const* d_in, const int* in_sizes, int n_in,
                              void* d_out, int out_size, void* d_ws, size_t ws_size,
                              hipStream_t stream) {
  const float* x       = (const float*)d_in[0];
  const float* wq_w    = (const float*)d_in[1];
  const float* wq_b    = (const float*)d_in[2];
  const float* wk_w    = (const float*)d_in[3];
  const float* wk_b    = (const float*)d_in[4];
  const float* wv_w    = (const float*)d_in[5];
  const float* wv_b    = (const float*)d_in[6];
  const float* dense_w = (const float*)d_in[7];
  const float* dense_b = (const float*)d_in[8];
  float* ws = (float*)d_ws;

  prep_k<<<(out_size + 255)/256, 256, 0, stream>>>(
      wq_w, wq_b, wk_w, wk_b, wv_w, wv_b, dense_w, ws, (float*)d_out, out_size);
  mha_fused<<<768, 256, 0, stream>>>(
      x, dense_w, dense_b,
      (const unsigned short*)(ws + 2560),   // wqT
      (const unsigned short*)(ws + 10752),  // wkT
      ws + 18944,                           // WVD
      ws + 19744,                           // bvd
      ws,                                   // pe
      (float*)d_out);
}